// Round 1
// baseline (1108.631 us; speedup 1.0000x reference)
//
#include <hip/hip_runtime.h>
#include <cfloat>
#include <cstdint>

// ---------------- problem constants ----------------
#define B_BATCH 32
#define D_DIM   256
#define HW      1024          // 32*32
#define N_POS   32768         // B_BATCH * HW
#define K_CODES 1024
#define DECAY_F   0.99f
#define ONE_M_DECAY 0.01f
#define EPS_F   1e-5f

// ---------------- output layout (floats) ----------------
#define OUT_Q    0                         // 8388608  quantized_st (B,C,H,W)
#define OUT_LOSS 8388608                   // 1
#define OUT_PERP 8388609                   // 1
#define OUT_CB   8388610                   // 262144   new_codebook
#define OUT_NCS  8650754                   // 1024     new_cluster_size
#define OUT_EDW  8651778                   // 262144   new_ema_dw

// ---------------- workspace layout (bytes) ----------------
#define WS_IDX     0          // 32768 * 4  (int)
#define WS_CBNORM  131072     // 1024 * 4
#define WS_COUNTS  135168     // 1024 * 4
#define WS_DW      139264     // 262144 * 4
#define WS_LOSS    1187840    // 4
#define WS_NTOT    1187844    // 4
#define WS_TOTAL   1187848

// ============================================================
// K0: codebook row squared norms. One wave per code.
__global__ __launch_bounds__(256) void cbnorm_kernel(const float* __restrict__ cb,
                                                     float* __restrict__ cbnorm) {
    int wave = threadIdx.x >> 6;
    int lane = threadIdx.x & 63;
    int k = blockIdx.x * 4 + wave;
    const float* row = cb + (size_t)k * D_DIM;
    float s = 0.f;
    #pragma unroll
    for (int j = 0; j < 4; ++j) {
        float v = row[lane + 64 * j];
        s += v * v;
    }
    #pragma unroll
    for (int off = 32; off >= 1; off >>= 1) s += __shfl_xor(s, off);
    if (lane == 0) cbnorm[k] = s;
}

// ============================================================
// A: argmin over K of ||c_k||^2 - 2 z.c_k for a 64-position tile.
// z viewed per batch as [D][HW] (position-contiguous).
__global__ __launch_bounds__(256) void argmin_kernel(const float* __restrict__ z,
                                                     const float* __restrict__ cb,
                                                     const float* __restrict__ cbnorm,
                                                     int* __restrict__ idx_out) {
    __shared__ float Zs[32][64];   // [d][n]
    __shared__ float Cs[32][68];   // [d][k]  padded

    const int n0  = blockIdx.x * 64;           // global position base
    const int b   = n0 >> 10;                  // /1024
    const int hw0 = n0 & 1023;
    const float* zb = z + (size_t)b * (D_DIM * HW) + hw0;  // zb[d*HW + n]

    const int tid = threadIdx.x;
    const int tx = tid & 15;     // k group
    const int ty = tid >> 4;     // n group
    const int k4 = tx * 4;
    const int n4 = ty * 4;

    float bestd[4] = {FLT_MAX, FLT_MAX, FLT_MAX, FLT_MAX};
    int   bestk[4] = {0, 0, 0, 0};

    // load-index precompute
    const int zn = tid & 63;           // n for Z loads
    const int zdb = (tid >> 6) * 8;    // d base for Z loads
    const int cd = tid & 31;           // d for C loads
    const int ckb = tid >> 5;          // k base for C loads

    for (int k0 = 0; k0 < K_CODES; k0 += 64) {
        float acc[4][4];
        #pragma unroll
        for (int i = 0; i < 4; ++i)
            #pragma unroll
            for (int j = 0; j < 4; ++j) acc[i][j] = 0.f;

        for (int d0 = 0; d0 < D_DIM; d0 += 32) {
            __syncthreads();
            // stage Z tile: 32 d-rows x 64 n, coalesced
            #pragma unroll
            for (int j = 0; j < 8; ++j) {
                int d = zdb + j;
                Zs[d][zn] = zb[(size_t)(d0 + d) * HW + zn];
            }
            // stage C tile transposed: Cs[d][k] = cb[(k0+k)*D + d0+d]
            #pragma unroll
            for (int j = 0; j < 8; ++j) {
                int k = ckb + j * 8;
                Cs[cd][k] = cb[(size_t)(k0 + k) * D_DIM + d0 + cd];
            }
            __syncthreads();

            #pragma unroll
            for (int dd = 0; dd < 32; ++dd) {
                float4 zv = *(const float4*)&Zs[dd][n4];
                float4 cv = *(const float4*)&Cs[dd][k4];
                acc[0][0] += zv.x * cv.x; acc[0][1] += zv.x * cv.y;
                acc[0][2] += zv.x * cv.z; acc[0][3] += zv.x * cv.w;
                acc[1][0] += zv.y * cv.x; acc[1][1] += zv.y * cv.y;
                acc[1][2] += zv.y * cv.z; acc[1][3] += zv.y * cv.w;
                acc[2][0] += zv.z * cv.x; acc[2][1] += zv.z * cv.y;
                acc[2][2] += zv.z * cv.z; acc[2][3] += zv.z * cv.w;
                acc[3][0] += zv.w * cv.x; acc[3][1] += zv.w * cv.y;
                acc[3][2] += zv.w * cv.z; acc[3][3] += zv.w * cv.w;
            }
        }
        // fold this k-tile into running argmin
        #pragma unroll
        for (int j = 0; j < 4; ++j) {
            int k = k0 + k4 + j;
            float cn = cbnorm[k];
            #pragma unroll
            for (int i = 0; i < 4; ++i) {
                float dist = cn - 2.f * acc[i][j];
                if (dist < bestd[i]) { bestd[i] = dist; bestk[i] = k; }
            }
        }
    }

    // reduce across the 16 threads sharing the same n rows (consecutive lanes)
    #pragma unroll
    for (int off = 1; off < 16; off <<= 1) {
        #pragma unroll
        for (int i = 0; i < 4; ++i) {
            float od = __shfl_xor(bestd[i], off);
            int   ok = __shfl_xor(bestk[i], off);
            if (od < bestd[i] || (od == bestd[i] && ok < bestk[i])) {
                bestd[i] = od; bestk[i] = ok;
            }
        }
    }
    if (tx == 0) {
        #pragma unroll
        for (int i = 0; i < 4; ++i) idx_out[n0 + n4 + i] = bestk[i];
    }
}

// ============================================================
// B: gather quantized + straight-through write, commitment loss,
//    counts and dw scatter. 4 consecutive hw per thread.
__global__ __launch_bounds__(256) void gather_kernel(const float* __restrict__ z,
                                                     const float* __restrict__ cb,
                                                     const int* __restrict__ idx,
                                                     float* __restrict__ outq,
                                                     float* __restrict__ dw,
                                                     float* __restrict__ counts,
                                                     float* __restrict__ lossacc) {
    __shared__ float red[256];
    const size_t e4 = ((size_t)blockIdx.x * 256 + threadIdx.x) * 4;
    const int hw = (int)(e4 & 1023);
    const int d  = (int)((e4 >> 10) & 255);
    const int b  = (int)(e4 >> 18);
    const int nb = b * HW + hw;

    float4 zv = *(const float4*)&z[e4];
    int k0 = idx[nb + 0], k1 = idx[nb + 1], k2 = idx[nb + 2], k3 = idx[nb + 3];
    float q0 = cb[(size_t)k0 * D_DIM + d];
    float q1 = cb[(size_t)k1 * D_DIM + d];
    float q2 = cb[(size_t)k2 * D_DIM + d];
    float q3 = cb[(size_t)k3 * D_DIM + d];

    float4 st;
    st.x = zv.x + (q0 - zv.x);
    st.y = zv.y + (q1 - zv.y);
    st.z = zv.z + (q2 - zv.z);
    st.w = zv.w + (q3 - zv.w);
    *(float4*)&outq[e4] = st;

    float d0 = zv.x - q0, d1 = zv.y - q1, d2 = zv.z - q2, d3 = zv.w - q3;
    float local = d0 * d0 + d1 * d1 + d2 * d2 + d3 * d3;

    atomicAdd(&dw[(size_t)k0 * D_DIM + d], zv.x);
    atomicAdd(&dw[(size_t)k1 * D_DIM + d], zv.y);
    atomicAdd(&dw[(size_t)k2 * D_DIM + d], zv.z);
    atomicAdd(&dw[(size_t)k3 * D_DIM + d], zv.w);
    if (d == 0) {
        atomicAdd(&counts[k0], 1.f);
        atomicAdd(&counts[k1], 1.f);
        atomicAdd(&counts[k2], 1.f);
        atomicAdd(&counts[k3], 1.f);
    }

    red[threadIdx.x] = local;
    __syncthreads();
    for (int s = 128; s >= 1; s >>= 1) {
        if (threadIdx.x < s) red[threadIdx.x] += red[threadIdx.x + s];
        __syncthreads();
    }
    if (threadIdx.x == 0) atomicAdd(lossacc, red[0]);
}

// ============================================================
// C1: new_cluster_size, n_total, perplexity, loss. One block.
__global__ __launch_bounds__(1024) void finalize_small(const float* __restrict__ ema_cs,
                                                       const float* __restrict__ counts,
                                                       const float* __restrict__ lossacc,
                                                       float* __restrict__ out_ncs,
                                                       float* __restrict__ out_loss,
                                                       float* __restrict__ out_perp,
                                                       float* __restrict__ ntot_ws) {
    __shared__ float s1[1024];
    __shared__ float s2[1024];
    int k = threadIdx.x;
    float cnt = counts[k];
    float ncs = ema_cs[k] * DECAY_F + ONE_M_DECAY * cnt;
    out_ncs[k] = ncs;
    float p = cnt / (float)N_POS;
    float pl = p * logf(p + 1e-10f);
    s1[k] = ncs;
    s2[k] = pl;
    __syncthreads();
    for (int s = 512; s >= 1; s >>= 1) {
        if (k < s) { s1[k] += s1[k + s]; s2[k] += s2[k + s]; }
        __syncthreads();
    }
    if (k == 0) {
        ntot_ws[0] = s1[0];
        out_perp[0] = expf(-s2[0]);
        out_loss[0] = 0.25f * lossacc[0] / 8388608.0f;
    }
}

// ============================================================
// C2: new_ema_dw and new_codebook. One block per code.
__global__ __launch_bounds__(256) void finalize_rows(const float* __restrict__ ema_dw,
                                                     const float* __restrict__ dw,
                                                     const float* __restrict__ out_ncs,
                                                     const float* __restrict__ ntot_ws,
                                                     float* __restrict__ out_edw,
                                                     float* __restrict__ out_cb) {
    int k = blockIdx.x;
    int d = threadIdx.x;
    float ncs = out_ncs[k];
    float nt = ntot_ws[0];
    float csz = (ncs + EPS_F) / (nt + (float)K_CODES * EPS_F) * nt;
    size_t e = (size_t)k * D_DIM + d;
    float ed = ema_dw[e] * DECAY_F + ONE_M_DECAY * dw[e];
    out_edw[e] = ed;
    out_cb[e] = ed / csz;
}

// ============================================================
extern "C" void kernel_launch(void* const* d_in, const int* in_sizes, int n_in,
                              void* d_out, int out_size, void* d_ws, size_t ws_size,
                              hipStream_t stream) {
    const float* z       = (const float*)d_in[0];
    const float* cb      = (const float*)d_in[1];
    const float* ema_cs  = (const float*)d_in[2];
    const float* ema_dw  = (const float*)d_in[3];
    float* out = (float*)d_out;

    char* ws = (char*)d_ws;
    int*   ws_idx    = (int*)(ws + WS_IDX);
    float* ws_cbnorm = (float*)(ws + WS_CBNORM);
    float* ws_counts = (float*)(ws + WS_COUNTS);
    float* ws_dw     = (float*)(ws + WS_DW);
    float* ws_loss   = (float*)(ws + WS_LOSS);
    float* ws_ntot   = (float*)(ws + WS_NTOT);

    hipMemsetAsync(d_ws, 0, WS_TOTAL, stream);

    cbnorm_kernel<<<K_CODES / 4, 256, 0, stream>>>(cb, ws_cbnorm);
    argmin_kernel<<<N_POS / 64, 256, 0, stream>>>(z, cb, ws_cbnorm, ws_idx);
    gather_kernel<<<8388608 / (256 * 4), 256, 0, stream>>>(
        z, cb, ws_idx, out + OUT_Q, ws_dw, ws_counts, ws_loss);
    finalize_small<<<1, 1024, 0, stream>>>(
        ema_cs, ws_counts, ws_loss, out + OUT_NCS, out + OUT_LOSS, out + OUT_PERP, ws_ntot);
    finalize_rows<<<K_CODES, 256, 0, stream>>>(
        ema_dw, ws_dw, out + OUT_NCS, ws_ntot, out + OUT_EDW, out + OUT_CB);
}

// Round 2
// 558.746 us; speedup vs baseline: 1.9841x; 1.9841x over previous
//
#include <hip/hip_runtime.h>
#include <cfloat>
#include <cstdint>

// ---------------- problem constants ----------------
#define B_BATCH 32
#define D_DIM   256
#define HW      1024          // 32*32
#define N_POS   32768         // B_BATCH * HW
#define K_CODES 1024
#define DECAY_F   0.99f
#define ONE_M_DECAY 0.01f
#define EPS_F   1e-5f

// ---------------- output layout (floats) ----------------
#define OUT_Q    0                         // 8388608  quantized_st (B,C,H,W)
#define OUT_LOSS 8388608                   // 1
#define OUT_PERP 8388609                   // 1
#define OUT_CB   8388610                   // 262144   new_codebook
#define OUT_NCS  8650754                   // 1024     new_cluster_size
#define OUT_EDW  8651778                   // 262144   new_ema_dw (used as dw scratch first)

// ---------------- workspace layout (bytes) ----------------
#define WS_COUNTS  0          // 1024*4   (float counts, histogrammed in argmin)
#define WS_LOSS    4096       // 4
#define WS_NTOT    4100       // 4
#define WS_MEMSET  4104       // bytes to zero at launch
#define WS_CBNORM  4352       // 1024*4
#define WS_OFFS    8448       // 1024*4 (int)
#define WS_CURSOR  12544      // 1024*4 (int)
#define WS_IDX     16640      // 32768*4 (int)
#define WS_SORTED  147712     // 32768*4 (int)
#define WS_ZT      278784     // 32768*256*4 = 33554432  (z_t[n][d], position-major)
#define WS_TOTAL   33833216

// ============================================================
// K0: codebook row squared norms. One wave per code.
__global__ __launch_bounds__(256) void cbnorm_kernel(const float* __restrict__ cb,
                                                     float* __restrict__ cbnorm) {
    int wave = threadIdx.x >> 6;
    int lane = threadIdx.x & 63;
    int k = blockIdx.x * 4 + wave;
    const float* row = cb + (size_t)k * D_DIM;
    float s = 0.f;
    #pragma unroll
    for (int j = 0; j < 4; ++j) {
        float v = row[lane + 64 * j];
        s += v * v;
    }
    #pragma unroll
    for (int off = 32; off >= 1; off >>= 1) s += __shfl_xor(s, off);
    if (lane == 0) cbnorm[k] = s;
}

// ============================================================
// A: argmin over K of ||c_k||^2 - 2 z.c_k for a 64-position tile.
// Also histograms counts (32K atomics total — cheap).
__global__ __launch_bounds__(256) void argmin_kernel(const float* __restrict__ z,
                                                     const float* __restrict__ cb,
                                                     const float* __restrict__ cbnorm,
                                                     int* __restrict__ idx_out,
                                                     float* __restrict__ counts) {
    __shared__ float Zs[32][64];   // [d][n]
    __shared__ float Cs[32][68];   // [d][k]  padded

    const int n0  = blockIdx.x * 64;           // global position base
    const int b   = n0 >> 10;                  // /1024
    const int hw0 = n0 & 1023;
    const float* zb = z + (size_t)b * (D_DIM * HW) + hw0;  // zb[d*HW + n]

    const int tid = threadIdx.x;
    const int tx = tid & 15;     // k group
    const int ty = tid >> 4;     // n group
    const int k4 = tx * 4;
    const int n4 = ty * 4;

    float bestd[4] = {FLT_MAX, FLT_MAX, FLT_MAX, FLT_MAX};
    int   bestk[4] = {0, 0, 0, 0};

    const int zn = tid & 63;           // n for Z loads
    const int zdb = (tid >> 6) * 8;    // d base for Z loads
    const int cd = tid & 31;           // d for C loads
    const int ckb = tid >> 5;          // k base for C loads

    for (int k0 = 0; k0 < K_CODES; k0 += 64) {
        float acc[4][4];
        #pragma unroll
        for (int i = 0; i < 4; ++i)
            #pragma unroll
            for (int j = 0; j < 4; ++j) acc[i][j] = 0.f;

        for (int d0 = 0; d0 < D_DIM; d0 += 32) {
            __syncthreads();
            #pragma unroll
            for (int j = 0; j < 8; ++j) {
                int d = zdb + j;
                Zs[d][zn] = zb[(size_t)(d0 + d) * HW + zn];
            }
            #pragma unroll
            for (int j = 0; j < 8; ++j) {
                int k = ckb + j * 8;
                Cs[cd][k] = cb[(size_t)(k0 + k) * D_DIM + d0 + cd];
            }
            __syncthreads();

            #pragma unroll
            for (int dd = 0; dd < 32; ++dd) {
                float4 zv = *(const float4*)&Zs[dd][n4];
                float4 cv = *(const float4*)&Cs[dd][k4];
                acc[0][0] += zv.x * cv.x; acc[0][1] += zv.x * cv.y;
                acc[0][2] += zv.x * cv.z; acc[0][3] += zv.x * cv.w;
                acc[1][0] += zv.y * cv.x; acc[1][1] += zv.y * cv.y;
                acc[1][2] += zv.y * cv.z; acc[1][3] += zv.y * cv.w;
                acc[2][0] += zv.z * cv.x; acc[2][1] += zv.z * cv.y;
                acc[2][2] += zv.z * cv.z; acc[2][3] += zv.z * cv.w;
                acc[3][0] += zv.w * cv.x; acc[3][1] += zv.w * cv.y;
                acc[3][2] += zv.w * cv.z; acc[3][3] += zv.w * cv.w;
            }
        }
        #pragma unroll
        for (int j = 0; j < 4; ++j) {
            int k = k0 + k4 + j;
            float cn = cbnorm[k];
            #pragma unroll
            for (int i = 0; i < 4; ++i) {
                float dist = cn - 2.f * acc[i][j];
                if (dist < bestd[i]) { bestd[i] = dist; bestk[i] = k; }
            }
        }
    }

    #pragma unroll
    for (int off = 1; off < 16; off <<= 1) {
        #pragma unroll
        for (int i = 0; i < 4; ++i) {
            float od = __shfl_xor(bestd[i], off);
            int   ok = __shfl_xor(bestk[i], off);
            if (od < bestd[i] || (od == bestd[i] && ok < bestk[i])) {
                bestd[i] = od; bestk[i] = ok;
            }
        }
    }
    if (tx == 0) {
        #pragma unroll
        for (int i = 0; i < 4; ++i) {
            idx_out[n0 + n4 + i] = bestk[i];
            atomicAdd(&counts[bestk[i]], 1.f);
        }
    }
}

// ============================================================
// Scan: exclusive prefix sum of counts -> offsets, plus a cursor copy.
__global__ __launch_bounds__(1024) void scan_kernel(const float* __restrict__ counts,
                                                    int* __restrict__ offsets,
                                                    int* __restrict__ cursor) {
    __shared__ int s[1024];
    int k = threadIdx.x;
    int c = (int)counts[k];
    s[k] = c;
    __syncthreads();
    for (int off = 1; off < 1024; off <<= 1) {
        int v = (k >= off) ? s[k - off] : 0;
        __syncthreads();
        s[k] += v;
        __syncthreads();
    }
    int excl = s[k] - c;
    offsets[k] = excl;
    cursor[k] = excl;
}

// ============================================================
// Scatter: sort position ids by code (order within a segment is arbitrary).
__global__ __launch_bounds__(256) void scatter_kernel(const int* __restrict__ idx,
                                                      int* __restrict__ cursor,
                                                      int* __restrict__ sorted) {
    int n = blockIdx.x * 256 + threadIdx.x;
    int k = idx[n];
    int pos = atomicAdd(&cursor[k], 1);
    sorted[pos] = n;
}

// ============================================================
// Fuse: read z once -> write outq (straight-through == gathered code),
// accumulate commitment loss, and materialize z_t[n][d] (position-major).
__global__ __launch_bounds__(256) void fuse_kernel(const float* __restrict__ z,
                                                   const float* __restrict__ cb,
                                                   const int* __restrict__ idx,
                                                   float* __restrict__ outq,
                                                   float* __restrict__ z_t,
                                                   float* __restrict__ lossacc) {
    __shared__ float Zs[32][65];
    __shared__ float Qs[32][65];
    __shared__ int kidx[64];
    __shared__ float red[256];

    const int tid = threadIdx.x;
    const int n0  = blockIdx.x * 64;
    const int b   = n0 >> 10;
    const int hw0 = n0 & 1023;
    const float* zb = z    + (size_t)b * (D_DIM * HW) + hw0;
    float*       ob = outq + (size_t)b * (D_DIM * HW) + hw0;

    if (tid < 64) kidx[tid] = idx[n0 + tid];

    const int zn = tid & 63;
    const int zdb = (tid >> 6) * 8;
    float loss = 0.f;

    for (int d0 = 0; d0 < D_DIM; d0 += 32) {
        __syncthreads();   // protects Zs/Qs reuse (and kidx on first iter)
        #pragma unroll
        for (int j = 0; j < 8; ++j)
            Zs[zdb + j][zn] = zb[(size_t)(d0 + zdb + j) * HW + zn];
        __syncthreads();

        // mapping A: per-(n, d4) — gather cb, write z_t, fill Qs, loss
        #pragma unroll
        for (int h = 0; h < 2; ++h) {
            int s  = tid + 256 * h;
            int n  = s >> 3;
            int dq = s & 7;
            int k  = kidx[n];
            float4 q = *(const float4*)&cb[(size_t)k * D_DIM + d0 + dq * 4];
            float4 zv;
            zv.x = Zs[dq * 4 + 0][n];
            zv.y = Zs[dq * 4 + 1][n];
            zv.z = Zs[dq * 4 + 2][n];
            zv.w = Zs[dq * 4 + 3][n];
            *(float4*)&z_t[(size_t)(n0 + n) * D_DIM + d0 + dq * 4] = zv;
            Qs[dq * 4 + 0][n] = q.x;
            Qs[dq * 4 + 1][n] = q.y;
            Qs[dq * 4 + 2][n] = q.z;
            Qs[dq * 4 + 3][n] = q.w;
            float dx = zv.x - q.x, dy = zv.y - q.y, dz = zv.z - q.z, dw = zv.w - q.w;
            loss += dx * dx + dy * dy + dz * dz + dw * dw;
        }
        __syncthreads();

        // mapping B: per-(d, n) — coalesced outq store
        #pragma unroll
        for (int j = 0; j < 8; ++j) {
            int v = tid + 256 * j;
            int d = v >> 6;
            int n = v & 63;
            float qq = Qs[d][n];
            float zz = Zs[d][n];
            ob[(size_t)(d0 + d) * HW + n] = zz + (qq - zz);  // match reference formula
        }
    }

    red[tid] = loss;
    __syncthreads();
    for (int s2 = 128; s2 >= 1; s2 >>= 1) {
        if (tid < s2) red[tid] += red[tid + s2];
        __syncthreads();
    }
    if (tid == 0) atomicAdd(lossacc, red[0]);
}

// ============================================================
// dw: one block per code; segmented sum over sorted positions, atomic-free.
// Writes into the new_ema_dw output region (finalized in place later).
__global__ __launch_bounds__(256) void dw_kernel(const float* __restrict__ z_t,
                                                 const int* __restrict__ sorted,
                                                 const int* __restrict__ offsets,
                                                 const float* __restrict__ counts,
                                                 float* __restrict__ dw) {
    __shared__ float part[4][256];
    const int k = blockIdx.x;
    const int start = offsets[k];
    const int cnt = (int)counts[k];
    const int w = threadIdx.x >> 6;
    const int lane = threadIdx.x & 63;

    float4 acc = {0.f, 0.f, 0.f, 0.f};
    for (int p = start + w; p < start + cnt; p += 4) {
        int id = sorted[p];
        float4 v = *(const float4*)&z_t[(size_t)id * D_DIM + lane * 4];
        acc.x += v.x; acc.y += v.y; acc.z += v.z; acc.w += v.w;
    }
    part[w][lane * 4 + 0] = acc.x;
    part[w][lane * 4 + 1] = acc.y;
    part[w][lane * 4 + 2] = acc.z;
    part[w][lane * 4 + 3] = acc.w;
    __syncthreads();
    int d = threadIdx.x;
    dw[(size_t)k * D_DIM + d] = part[0][d] + part[1][d] + part[2][d] + part[3][d];
}

// ============================================================
// C1: new_cluster_size, n_total, perplexity, loss. One block.
__global__ __launch_bounds__(1024) void finalize_small(const float* __restrict__ ema_cs,
                                                       const float* __restrict__ counts,
                                                       const float* __restrict__ lossacc,
                                                       float* __restrict__ out_ncs,
                                                       float* __restrict__ out_loss,
                                                       float* __restrict__ out_perp,
                                                       float* __restrict__ ntot_ws) {
    __shared__ float s1[1024];
    __shared__ float s2[1024];
    int k = threadIdx.x;
    float cnt = counts[k];
    float ncs = ema_cs[k] * DECAY_F + ONE_M_DECAY * cnt;
    out_ncs[k] = ncs;
    float p = cnt / (float)N_POS;
    float pl = p * logf(p + 1e-10f);
    s1[k] = ncs;
    s2[k] = pl;
    __syncthreads();
    for (int s = 512; s >= 1; s >>= 1) {
        if (k < s) { s1[k] += s1[k + s]; s2[k] += s2[k + s]; }
        __syncthreads();
    }
    if (k == 0) {
        ntot_ws[0] = s1[0];
        out_perp[0] = expf(-s2[0]);
        out_loss[0] = 0.25f * lossacc[0] / 8388608.0f;
    }
}

// ============================================================
// C2: new_ema_dw and new_codebook. dw is read from out_edw and
// overwritten in place.
__global__ __launch_bounds__(256) void finalize_rows(const float* __restrict__ ema_dw,
                                                     const float* __restrict__ out_ncs,
                                                     const float* __restrict__ ntot_ws,
                                                     float* __restrict__ out_edw,
                                                     float* __restrict__ out_cb) {
    int k = blockIdx.x;
    int d = threadIdx.x;
    float ncs = out_ncs[k];
    float nt = ntot_ws[0];
    float csz = (ncs + EPS_F) / (nt + (float)K_CODES * EPS_F) * nt;
    size_t e = (size_t)k * D_DIM + d;
    float ed = ema_dw[e] * DECAY_F + ONE_M_DECAY * out_edw[e];
    out_edw[e] = ed;
    out_cb[e] = ed / csz;
}

// ============================================================
extern "C" void kernel_launch(void* const* d_in, const int* in_sizes, int n_in,
                              void* d_out, int out_size, void* d_ws, size_t ws_size,
                              hipStream_t stream) {
    const float* z       = (const float*)d_in[0];
    const float* cb      = (const float*)d_in[1];
    const float* ema_cs  = (const float*)d_in[2];
    const float* ema_dw  = (const float*)d_in[3];
    float* out = (float*)d_out;

    char* ws = (char*)d_ws;
    float* ws_counts = (float*)(ws + WS_COUNTS);
    float* ws_loss   = (float*)(ws + WS_LOSS);
    float* ws_ntot   = (float*)(ws + WS_NTOT);
    float* ws_cbnorm = (float*)(ws + WS_CBNORM);
    int*   ws_offs   = (int*)(ws + WS_OFFS);
    int*   ws_cursor = (int*)(ws + WS_CURSOR);
    int*   ws_idx    = (int*)(ws + WS_IDX);
    int*   ws_sorted = (int*)(ws + WS_SORTED);
    float* ws_zt     = (float*)(ws + WS_ZT);

    hipMemsetAsync(d_ws, 0, WS_MEMSET, stream);

    cbnorm_kernel<<<K_CODES / 4, 256, 0, stream>>>(cb, ws_cbnorm);
    argmin_kernel<<<N_POS / 64, 256, 0, stream>>>(z, cb, ws_cbnorm, ws_idx, ws_counts);
    scan_kernel<<<1, 1024, 0, stream>>>(ws_counts, ws_offs, ws_cursor);
    scatter_kernel<<<N_POS / 256, 256, 0, stream>>>(ws_idx, ws_cursor, ws_sorted);
    fuse_kernel<<<N_POS / 64, 256, 0, stream>>>(z, cb, ws_idx, out + OUT_Q, ws_zt, ws_loss);
    dw_kernel<<<K_CODES, 256, 0, stream>>>(ws_zt, ws_sorted, ws_offs, ws_counts, out + OUT_EDW);
    finalize_small<<<1, 1024, 0, stream>>>(
        ema_cs, ws_counts, ws_loss, out + OUT_NCS, out + OUT_LOSS, out + OUT_PERP, ws_ntot);
    finalize_rows<<<K_CODES, 256, 0, stream>>>(
        ema_dw, out + OUT_NCS, ws_ntot, out + OUT_EDW, out + OUT_CB);
}